// Round 2
// baseline (123.271 us; speedup 1.0000x reference)
//
#include <hip/hip_runtime.h>
#include <hip/hip_bf16.h>
#include <stdint.h>

// Problem constants (from reference setup_inputs)
#define L_DIM 2048
#define B_DIM 32
#define E_DIM 512
#define HID_DIM 512
#define M_DIM (L_DIM * B_DIM)   // 65536 rows, row m = l*32 + b

typedef float f32x4 __attribute__((ext_vector_type(4)));
typedef short bf16x8 __attribute__((ext_vector_type(8)));

// ws layout (bytes); requires ws_size >= 3211264 (~3.1 MB)
#define OFF_BASE  0         // 32*512 f32          = 65536
#define OFF_WT    65536     // 512*512 bf16        = 524288  -> 589824
#define OFF_LOGIT 589824    // 65536 f32           = 262144  -> 851968
#define OFF_P     851968    // 65536 f32           = 262144  -> 1114112
#define OFF_PART  1114112   // 32*32*512 f32       = 2097152 -> 3211264

__device__ __forceinline__ unsigned short f2bf(float f) {
  unsigned int u = __float_as_uint(f);
  u = (u + 0x7FFFu + ((u >> 16) & 1u)) >> 16;   // RNE
  return (unsigned short)u;
}

__device__ __forceinline__ float tanh_fast(float x) {
  float xc = fminf(fmaxf(x, -15.f), 15.f);
  float e = __expf(2.f * xc);
  return (e - 1.f) * __builtin_amdgcn_rcpf(e + 1.f);
}

__device__ __forceinline__ uint4 pack8(const float4& a, const float4& b) {
  uint4 r;
  r.x = (unsigned)f2bf(a.x) | ((unsigned)f2bf(a.y) << 16);
  r.y = (unsigned)f2bf(a.z) | ((unsigned)f2bf(a.w) << 16);
  r.z = (unsigned)f2bf(b.x) | ((unsigned)f2bf(b.y) << 16);
  r.w = (unsigned)f2bf(b.z) | ((unsigned)f2bf(b.w) << 16);
  return r;
}

// ---------------- kernel 1: base[b][h] = hidden[b]@W1_h + b1 ----------------
__global__ __launch_bounds__(256) void k_base(const float* __restrict__ hidden,
                                              const float* __restrict__ W1,
                                              const float* __restrict__ b1,
                                              float* __restrict__ base) {
  const int b = blockIdx.x;
  const int tid = threadIdx.x;
  __shared__ float hs[HID_DIM];
  {
    float2 v = *(const float2*)(hidden + (size_t)b * 512 + tid * 2);
    hs[tid * 2] = v.x; hs[tid * 2 + 1] = v.y;
  }
  __syncthreads();
  const int h = tid * 2;
  float2 b1v = *(const float2*)(b1 + h);
  float ax = b1v.x, ay = b1v.y;
#pragma unroll 8
  for (int e = 0; e < 512; ++e) {
    float2 w = *(const float2*)(W1 + (size_t)e * 512 + h);
    float hv = hs[e];
    ax = fmaf(hv, w.x, ax);
    ay = fmaf(hv, w.y, ay);
  }
  float2 r; r.x = ax; r.y = ay;
  *(float2*)(base + (size_t)b * 512 + h) = r;
}

// ------- kernel 2: Wt[kc][n][kl] = bf16(W1_e[kc*32+kl][n]) (transpose) ------
__global__ __launch_bounds__(256) void k_prep_wt(const float* __restrict__ W1,
                                                 unsigned short* __restrict__ Wt) {
  const int kc = blockIdx.x;   // 16 blocks
  const int tid = threadIdx.x;
  __shared__ unsigned short sh[32][520];   // +8 pad to break bank conflicts
#pragma unroll
  for (int i = 0; i < 16; ++i) {
    int flat4 = i * 256 + tid;              // 4096 float4 total
    int r = flat4 >> 7;                     // 0..31
    int c = (flat4 & 127) * 4;              // 0..508
    float4 v = *(const float4*)(W1 + (size_t)(512 + kc * 32 + r) * 512 + c);
    sh[r][c + 0] = f2bf(v.x); sh[r][c + 1] = f2bf(v.y);
    sh[r][c + 2] = f2bf(v.z); sh[r][c + 3] = f2bf(v.w);
  }
  __syncthreads();
#pragma unroll
  for (int j = 0; j < 2; ++j) {
    int n = tid * 2 + j;
    alignas(16) unsigned short ov[32];
#pragma unroll
    for (int kl = 0; kl < 32; ++kl) ov[kl] = sh[kl][n];
    uint4* dst = (uint4*)(Wt + ((size_t)kc * 16384 + (size_t)n * 32));
    const uint4* s = (const uint4*)ov;
    dst[0] = s[0]; dst[1] = s[1]; dst[2] = s[2]; dst[3] = s[3];
  }
}

// ------- kernel 3: fused GEMM + tanh + W2 reduce -> logit[m] ---------------
// BM=128 rows/block, full N=512 in-block. 8 waves, wave tile 64x128.
// LDS: x chunk [128][32] bf16 dbuf (16KB) + W chunk [512][32] bf16 dbuf (64KB).
__global__ __launch_bounds__(512, 2) void k_logits(
    const float* __restrict__ x, const unsigned short* __restrict__ Wt,
    const float* __restrict__ base, const float* __restrict__ W2,
    float* __restrict__ logit) {
  __shared__ unsigned short xs[2][128 * 32];
  __shared__ unsigned short wl[2][512 * 32];
  const int tid = threadIdx.x;
  const int m0 = blockIdx.x * 128;
  const int wid = tid >> 6, lane = tid & 63;
  const int wm = wid >> 2, wn = wid & 3;       // 2 M-waves x 4 N-waves
  const int lg = lane >> 4, l15 = lane & 15;

  const int xr = tid >> 2;              // 0..127 row in tile
  const int xk = (tid & 3) * 8;         // k sub-offset within 32-chunk
  const float* xsrc = x + (size_t)(m0 + xr) * 512 + xk;

  // ---- prologue: stage kc=0 ----
  {
    float4 a0 = *(const float4*)(xsrc + 0);
    float4 a1 = *(const float4*)(xsrc + 4);
    const uint4* s = (const uint4*)(Wt + (size_t)tid * 32);
    uint4 w0 = s[0], w1 = s[1], w2_ = s[2], w3 = s[3];
    *(uint4*)(&xs[0][xr * 32 + xk]) = pack8(a0, a1);
    uint4* wd = (uint4*)(&wl[0][tid * 32]);
    wd[(0 + tid) & 3] = w0; wd[(1 + tid) & 3] = w1;
    wd[(2 + tid) & 3] = w2_; wd[(3 + tid) & 3] = w3;
  }
  __syncthreads();

  f32x4 acc[4][8];
#pragma unroll
  for (int mi = 0; mi < 4; ++mi)
#pragma unroll
    for (int ni = 0; ni < 8; ++ni) acc[mi][ni] = (f32x4){0.f, 0.f, 0.f, 0.f};

  for (int kc = 0; kc < 16; ++kc) {
    const int cur = kc & 1;
    float4 nxa, nxb; uint4 nw0, nw1, nw2, nw3;
    if (kc < 15) {   // issue next-chunk global loads early (hide under MFMA)
      nxa = *(const float4*)(xsrc + (kc + 1) * 32);
      nxb = *(const float4*)(xsrc + (kc + 1) * 32 + 4);
      const uint4* s = (const uint4*)(Wt + (size_t)(kc + 1) * 16384 + (size_t)tid * 32);
      nw0 = s[0]; nw1 = s[1]; nw2 = s[2]; nw3 = s[3];
    }
    bf16x8 af[4];
#pragma unroll
    for (int mi = 0; mi < 4; ++mi) {
      int r = wm * 64 + mi * 16 + l15;
      af[mi] = *(const bf16x8*)(&xs[cur][r * 32 + lg * 8]);
    }
    bf16x8 bf[8];
#pragma unroll
    for (int ni = 0; ni < 8; ++ni) {
      int n = wn * 128 + ni * 16 + l15;
      bf[ni] = *(const bf16x8*)(&wl[cur][n * 32 + ((lg + n) & 3) * 8]);
    }
#pragma unroll
    for (int mi = 0; mi < 4; ++mi)
#pragma unroll
      for (int ni = 0; ni < 8; ++ni)
        acc[mi][ni] = __builtin_amdgcn_mfma_f32_16x16x32_bf16(af[mi], bf[ni], acc[mi][ni], 0, 0, 0);
    if (kc < 15) {
      const int nb = cur ^ 1;
      *(uint4*)(&xs[nb][xr * 32 + xk]) = pack8(nxa, nxb);
      uint4* wd = (uint4*)(&wl[nb][tid * 32]);
      wd[(0 + tid) & 3] = nw0; wd[(1 + tid) & 3] = nw1;
      wd[(2 + tid) & 3] = nw2; wd[(3 + tid) & 3] = nw3;
    }
    __syncthreads();
  }

  // ---- epilogue: pre += base; tanh; dot with W2; reduce over h ----
  float w2v[8];
#pragma unroll
  for (int ni = 0; ni < 8; ++ni) w2v[ni] = W2[wn * 128 + ni * 16 + l15];
  float lsum[4][4];
#pragma unroll
  for (int mi = 0; mi < 4; ++mi) {
#pragma unroll
    for (int rg = 0; rg < 4; ++rg) {
      int m = m0 + wm * 64 + mi * 16 + lg * 4 + rg;
      int bb = m & 31;
      const float* brow = base + (size_t)bb * 512 + wn * 128;
      float s = 0.f;
#pragma unroll
      for (int ni = 0; ni < 8; ++ni) {
        float pre = acc[mi][ni][rg] + brow[ni * 16 + l15];
        s = fmaf(tanh_fast(pre), w2v[ni], s);
      }
      lsum[mi][rg] = s;
    }
  }
  // Cross-wave reduction over the 4 N-waves (wn). Each wave holds the partial
  // dot over its 128 cols for its 64 rows. Alias scratch onto xs (dead now;
  // last K-loop __syncthreads() ordered all reads before this point).
  float (*lred)[4][64] = (float (*)[4][64])xs;   // [wm][wn][row-in-64], 2 KB
#pragma unroll
  for (int mi = 0; mi < 4; ++mi)
#pragma unroll
    for (int rg = 0; rg < 4; ++rg) {
      float v = lsum[mi][rg];
      v += __shfl_xor(v, 1); v += __shfl_xor(v, 2);
      v += __shfl_xor(v, 4); v += __shfl_xor(v, 8);
      if (l15 == 0) lred[wm][wn][mi * 16 + lg * 4 + rg] = v;
    }
  __syncthreads();
  if (tid < 128) {
    const int wmr = tid >> 6, row = tid & 63;
    float v = (lred[wmr][0][row] + lred[wmr][1][row]) +
              (lred[wmr][2][row] + lred[wmr][3][row]);
    logit[m0 + tid] = v;
  }
}

// ---------------- kernel 4: masked softmax over L per b ----------------
__global__ __launch_bounds__(256) void k_softmax(const float* __restrict__ logit,
                                                 const int* __restrict__ mask,
                                                 float* __restrict__ p) {
  const int b = blockIdx.x, tid = threadIdx.x;
  float lv[8]; float mx = -3.0e38f;
#pragma unroll
  for (int i = 0; i < 8; ++i) {
    int idx = (tid + i * 256) * 32 + b;
    float v = (mask[idx] != 0) ? logit[idx] : -1.0e10f;
    lv[i] = v; mx = fmaxf(mx, v);
  }
  __shared__ float red[8];
  for (int d = 1; d < 64; d <<= 1) mx = fmaxf(mx, __shfl_xor(mx, d));
  if ((tid & 63) == 0) red[tid >> 6] = mx;
  __syncthreads();
  mx = fmaxf(fmaxf(red[0], red[1]), fmaxf(red[2], red[3]));
  float s = 0.f;
#pragma unroll
  for (int i = 0; i < 8; ++i) { lv[i] = __expf(lv[i] - mx); s += lv[i]; }
  for (int d = 1; d < 64; d <<= 1) s += __shfl_xor(s, d);
  __syncthreads();
  if ((tid & 63) == 0) red[4 + (tid >> 6)] = s;
  __syncthreads();
  s = (red[4] + red[5]) + (red[6] + red[7]);
  float inv = 1.f / s;
#pragma unroll
  for (int i = 0; i < 8; ++i) {
    int idx = (tid + i * 256) * 32 + b;
    p[idx] = lv[i] * inv;
  }
}

// ------- kernel 5: partial ctx: part[b][ch][e] = sum_{l in ch} p*x ---------
__global__ __launch_bounds__(256) void k_ctx(const float* __restrict__ x,
                                             const float* __restrict__ p,
                                             float* __restrict__ part) {
  const int blk = blockIdx.x;            // 1024 = 32 b * 32 chunks
  const int b = blk >> 5, ch = blk & 31;
  const int tid = threadIdx.x;
  __shared__ float ps[64];
  const int l0 = ch * 64;
  if (tid < 64) ps[tid] = p[(l0 + tid) * 32 + b];
  __syncthreads();
  const float* xb = x + ((size_t)l0 * 32 + b) * 512 + tid * 2;
  float ax = 0.f, ay = 0.f;
#pragma unroll 4
  for (int i = 0; i < 64; ++i) {
    float2 v = *(const float2*)(xb + (size_t)i * 32 * 512);
    float pv = ps[i];
    ax = fmaf(pv, v.x, ax); ay = fmaf(pv, v.y, ay);
  }
  float2 r; r.x = ax; r.y = ay;
  *(float2*)(part + (size_t)blk * 512 + tid * 2) = r;
}

// ------- kernel 6: reduce partials -> ctx, concat action_feature -----------
__global__ __launch_bounds__(256) void k_final(const float* __restrict__ part,
                                               const float* __restrict__ af,
                                               float* __restrict__ out) {
  const int b = blockIdx.x, tid = threadIdx.x;
  float ax = 0.f, ay = 0.f;
#pragma unroll
  for (int ch = 0; ch < 32; ++ch) {
    float2 v = *(const float2*)(part + ((size_t)(b * 32 + ch) * 512) + tid * 2);
    ax += v.x; ay += v.y;
  }
  float2 r; r.x = ax; r.y = ay;
  *(float2*)(out + (size_t)b * 1024 + tid * 2) = r;
  float2 a = *(const float2*)(af + (size_t)b * 512 + tid * 2);
  *(float2*)(out + (size_t)b * 1024 + 512 + tid * 2) = a;
}

extern "C" void kernel_launch(void* const* d_in, const int* in_sizes, int n_in,
                              void* d_out, int out_size, void* d_ws, size_t ws_size,
                              hipStream_t stream) {
  const float* x      = (const float*)d_in[0];
  const int*   mask   = (const int*)d_in[1];
  const float* af     = (const float*)d_in[2];
  const float* hidden = (const float*)d_in[3];
  // d_in[4] = state (unused by reference output)
  const float* W1     = (const float*)d_in[5];
  const float* b1     = (const float*)d_in[6];
  const float* W2     = (const float*)d_in[7];
  // d_in[8] = b2 (softmax-invariant, skipped)
  float* out = (float*)d_out;
  char* ws = (char*)d_ws;
  float*          base  = (float*)(ws + OFF_BASE);
  unsigned short* Wt    = (unsigned short*)(ws + OFF_WT);
  float*          logit = (float*)(ws + OFF_LOGIT);
  float*          p     = (float*)(ws + OFF_P);
  float*          part  = (float*)(ws + OFF_PART);

  k_base   <<<32,   256, 0, stream>>>(hidden, W1, b1, base);
  k_prep_wt<<<16,   256, 0, stream>>>(W1, Wt);
  k_logits <<<512,  512, 0, stream>>>(x, Wt, base, W2, logit);
  k_softmax<<<32,   256, 0, stream>>>(logit, mask, p);
  k_ctx    <<<1024, 256, 0, stream>>>(x, p, part);
  k_final  <<<32,   256, 0, stream>>>(part, af, out);
}

// Round 3
// 118.534 us; speedup vs baseline: 1.0400x; 1.0400x over previous
//
#include <hip/hip_runtime.h>
#include <hip/hip_bf16.h>
#include <stdint.h>

// Problem constants (from reference setup_inputs)
#define L_DIM 2048
#define B_DIM 32
#define E_DIM 512
#define HID_DIM 512
#define M_DIM (L_DIM * B_DIM)   // 65536 rows, row m = l*32 + b

typedef float f32x4 __attribute__((ext_vector_type(4)));
typedef short bf16x8 __attribute__((ext_vector_type(8)));

// ws layout (bytes); requires ws_size >= 3211264 (~3.1 MB) — same as R2 (known OK)
#define OFF_BASE  0         // 32*512 f32          = 65536
#define OFF_WT    65536     // 512*512 bf16        = 524288  -> 589824
#define OFF_LOGIT 589824    // 65536 f32           = 262144  -> 851968
#define OFF_P     851968    // 65536 f32           = 262144  -> 1114112
#define OFF_PART  1114112   // 32*32*512 f32       = 2097152 -> 3211264

__device__ __forceinline__ unsigned short f2bf(float f) {
  unsigned int u = __float_as_uint(f);
  u = (u + 0x7FFFu + ((u >> 16) & 1u)) >> 16;   // RNE
  return (unsigned short)u;
}

__device__ __forceinline__ float tanh_fast(float x) {
  float xc = fminf(fmaxf(x, -15.f), 15.f);
  float e = __expf(2.f * xc);
  return (e - 1.f) * __builtin_amdgcn_rcpf(e + 1.f);
}

__device__ __forceinline__ uint4 pack8(const float4& a, const float4& b) {
  uint4 r;
  r.x = (unsigned)f2bf(a.x) | ((unsigned)f2bf(a.y) << 16);
  r.y = (unsigned)f2bf(a.z) | ((unsigned)f2bf(a.w) << 16);
  r.z = (unsigned)f2bf(b.x) | ((unsigned)f2bf(b.y) << 16);
  r.w = (unsigned)f2bf(b.z) | ((unsigned)f2bf(b.w) << 16);
  return r;
}

// ---------------- kernel 1: base[b][h] = hidden[b]@W1_h + b1 ----------------
__global__ __launch_bounds__(256) void k_base(const float* __restrict__ hidden,
                                              const float* __restrict__ W1,
                                              const float* __restrict__ b1,
                                              float* __restrict__ base) {
  const int b = blockIdx.x;
  const int tid = threadIdx.x;
  __shared__ float hs[HID_DIM];
  {
    float2 v = *(const float2*)(hidden + (size_t)b * 512 + tid * 2);
    hs[tid * 2] = v.x; hs[tid * 2 + 1] = v.y;
  }
  __syncthreads();
  const int h = tid * 2;
  float2 b1v = *(const float2*)(b1 + h);
  float ax = b1v.x, ay = b1v.y;
#pragma unroll 8
  for (int e = 0; e < 512; ++e) {
    float2 w = *(const float2*)(W1 + (size_t)e * 512 + h);
    float hv = hs[e];
    ax = fmaf(hv, w.x, ax);
    ay = fmaf(hv, w.y, ay);
  }
  float2 r; r.x = ax; r.y = ay;
  *(float2*)(base + (size_t)b * 512 + h) = r;
}

// ------- kernel 2: pre-permute W1_e into MFMA-fragment order ------
// Wt unit index (16B units, 2048 per kc): u = wn*512 + ni*64 + lg*16 + l15
// content: 8 bf16 of W1_e[k = kc*32 + lg*8 + j][n = wn*128 + ni*16 + l15]
__global__ __launch_bounds__(256) void k_prep_wt(const float* __restrict__ W1,
                                                 unsigned short* __restrict__ Wt) {
  const int kc = blockIdx.x;   // 16 blocks
  const int tid = threadIdx.x;
  __shared__ unsigned short sh[32][516];   // +4 pad to spread strided col reads
#pragma unroll
  for (int i = 0; i < 16; ++i) {
    int f4 = i * 256 + tid;                 // 4096 float4 total
    int r = f4 >> 7;                        // 0..31
    int c = (f4 & 127) * 4;                 // 0..508
    float4 v = *(const float4*)(W1 + (size_t)(512 + kc * 32 + r) * 512 + c);
    sh[r][c + 0] = f2bf(v.x); sh[r][c + 1] = f2bf(v.y);
    sh[r][c + 2] = f2bf(v.z); sh[r][c + 3] = f2bf(v.w);
  }
  __syncthreads();
#pragma unroll
  for (int i = 0; i < 8; ++i) {
    int u = i * 256 + tid;                  // 0..2047
    int n = ((u >> 9) << 7) + (((u >> 6) & 7) << 4) + (u & 15);
    int k0 = ((u >> 4) & 3) << 3;
    alignas(16) unsigned short tmp[8];
#pragma unroll
    for (int j = 0; j < 8; ++j) tmp[j] = sh[k0 + j][n];
    *(uint4*)(Wt + ((size_t)kc * 2048 + u) * 8) = *(const uint4*)tmp;
  }
}

// ------- kernel 3: fused GEMM + tanh + W2 reduce -> logit[m] ---------------
// BM=128, BN=512 (full N), 8 waves 2Mx4N, wave tile 64x128.
// LDS in fragment order: every ds_read/ds_write is lane-linear (0 conflicts).
__global__ __launch_bounds__(512, 2) void k_logits(
    const float* __restrict__ x, const unsigned short* __restrict__ Wt,
    const float* __restrict__ base, const float* __restrict__ W2,
    float* __restrict__ logit) {
  __shared__ unsigned short xs[2][4096];    // 512 units/buf (8 KB each)
  __shared__ unsigned short wl[2][16384];   // 2048 units/buf (32 KB each)
  const int tid = threadIdx.x;
  const int m0 = blockIdx.x * 128;
  const int wid = tid >> 6, lane = tid & 63;
  const int wm = wid >> 2, wn = wid & 3;       // 2 M-waves x 4 N-waves
  const int lg = lane >> 4, l15 = lane & 15;

  const int xr = tid >> 2;              // row 0..127 in tile
  const int xks = tid & 3;              // 8-elem k-segment
  const float* xsrc = x + (size_t)(m0 + xr) * 512 + xks * 8;
  const int xu = ((xr >> 4) << 6) + (xks << 4) + (xr & 15);  // frag-order unit

  // ---- prologue: stage kc=0 ----
  {
    float4 a0 = *(const float4*)(xsrc + 0);
    float4 a1 = *(const float4*)(xsrc + 4);
    *(uint4*)(&xs[0][xu * 8]) = pack8(a0, a1);
    const uint4* s = (const uint4*)Wt;
#pragma unroll
    for (int j = 0; j < 4; ++j) {
      uint4 w = s[j * 512 + tid];
      *(uint4*)(&wl[0][(j * 512 + tid) * 8]) = w;
    }
  }
  __syncthreads();

  f32x4 acc[4][8];
#pragma unroll
  for (int mi = 0; mi < 4; ++mi)
#pragma unroll
    for (int ni = 0; ni < 8; ++ni) acc[mi][ni] = (f32x4){0.f, 0.f, 0.f, 0.f};

  for (int kc = 0; kc < 16; ++kc) {
    const int cur = kc & 1;
    float4 nxa, nxb; uint4 nw[4];
    if (kc < 15) {   // issue next-chunk global loads early (hide under MFMA/LDS)
      nxa = *(const float4*)(xsrc + (kc + 1) * 32);
      nxb = *(const float4*)(xsrc + (kc + 1) * 32 + 4);
      const uint4* s = (const uint4*)(Wt) + (size_t)(kc + 1) * 2048;
#pragma unroll
      for (int j = 0; j < 4; ++j) nw[j] = s[j * 512 + tid];
    }
    bf16x8 af[4];
#pragma unroll
    for (int mi = 0; mi < 4; ++mi)
      af[mi] = *(const bf16x8*)(&xs[cur][((wm * 4 + mi) * 64 + lane) * 8]);
    bf16x8 bfv[8];
#pragma unroll
    for (int ni = 0; ni < 8; ++ni)
      bfv[ni] = *(const bf16x8*)(&wl[cur][(wn * 512 + ni * 64 + lane) * 8]);
#pragma unroll
    for (int mi = 0; mi < 4; ++mi)
#pragma unroll
      for (int ni = 0; ni < 8; ++ni)
        acc[mi][ni] = __builtin_amdgcn_mfma_f32_16x16x32_bf16(af[mi], bfv[ni], acc[mi][ni], 0, 0, 0);
    if (kc < 15) {
      const int nb = cur ^ 1;
      *(uint4*)(&xs[nb][xu * 8]) = pack8(nxa, nxb);
#pragma unroll
      for (int j = 0; j < 4; ++j)
        *(uint4*)(&wl[nb][(j * 512 + tid) * 8]) = nw[j];
    }
    __syncthreads();
  }

  // ---- epilogue: pre += base; tanh; dot with W2; reduce over h ----
  float w2v[8];
#pragma unroll
  for (int ni = 0; ni < 8; ++ni) w2v[ni] = W2[wn * 128 + ni * 16 + l15];
  float lsum[4][4];
#pragma unroll
  for (int mi = 0; mi < 4; ++mi) {
#pragma unroll
    for (int rg = 0; rg < 4; ++rg) {
      int m = m0 + wm * 64 + mi * 16 + lg * 4 + rg;
      int bb = m & 31;
      const float* brow = base + (size_t)bb * 512 + wn * 128;
      float s = 0.f;
#pragma unroll
      for (int ni = 0; ni < 8; ++ni) {
        float pre = acc[mi][ni][rg] + brow[ni * 16 + l15];
        s = fmaf(tanh_fast(pre), w2v[ni], s);
      }
      lsum[mi][rg] = s;
    }
  }
  // Cross-wave reduction over the 4 N-waves. Alias scratch onto xs (dead now).
  float (*lred)[4][64] = (float (*)[4][64])xs;   // [wm][wn][row-in-64], 2 KB
#pragma unroll
  for (int mi = 0; mi < 4; ++mi)
#pragma unroll
    for (int rg = 0; rg < 4; ++rg) {
      float v = lsum[mi][rg];
      v += __shfl_xor(v, 1); v += __shfl_xor(v, 2);
      v += __shfl_xor(v, 4); v += __shfl_xor(v, 8);
      if (l15 == 0) lred[wm][wn][mi * 16 + lg * 4 + rg] = v;
    }
  __syncthreads();
  if (tid < 128) {
    const int wmr = tid >> 6, row = tid & 63;
    float v = (lred[wmr][0][row] + lred[wmr][1][row]) +
              (lred[wmr][2][row] + lred[wmr][3][row]);
    logit[m0 + tid] = v;
  }
}

// ---------------- kernel 4: masked softmax over L per b ----------------
__global__ __launch_bounds__(256) void k_softmax(const float* __restrict__ logit,
                                                 const int* __restrict__ mask,
                                                 float* __restrict__ p) {
  const int b = blockIdx.x, tid = threadIdx.x;
  float lv[8]; float mx = -3.0e38f;
#pragma unroll
  for (int i = 0; i < 8; ++i) {
    int idx = (tid + i * 256) * 32 + b;
    float v = (mask[idx] != 0) ? logit[idx] : -1.0e10f;
    lv[i] = v; mx = fmaxf(mx, v);
  }
  __shared__ float red[8];
  for (int d = 1; d < 64; d <<= 1) mx = fmaxf(mx, __shfl_xor(mx, d));
  if ((tid & 63) == 0) red[tid >> 6] = mx;
  __syncthreads();
  mx = fmaxf(fmaxf(red[0], red[1]), fmaxf(red[2], red[3]));
  float s = 0.f;
#pragma unroll
  for (int i = 0; i < 8; ++i) { lv[i] = __expf(lv[i] - mx); s += lv[i]; }
  for (int d = 1; d < 64; d <<= 1) s += __shfl_xor(s, d);
  __syncthreads();
  if ((tid & 63) == 0) red[4 + (tid >> 6)] = s;
  __syncthreads();
  s = (red[4] + red[5]) + (red[6] + red[7]);
  float inv = 1.f / s;
#pragma unroll
  for (int i = 0; i < 8; ++i) {
    int idx = (tid + i * 256) * 32 + b;
    p[idx] = lv[i] * inv;
  }
}

// ------- kernel 5: partial ctx: part[b][ch][e] = sum_{l in ch} p*x ---------
__global__ __launch_bounds__(128) void k_ctx(const float* __restrict__ x,
                                             const float* __restrict__ p,
                                             float* __restrict__ part) {
  const int blk = blockIdx.x;            // 1024 = 32 b * 32 chunks
  const int b = blk >> 5, ch = blk & 31;
  const int tid = threadIdx.x;           // 128 threads, float4 each
  __shared__ float ps[64];
  const int l0 = ch * 64;
  if (tid < 64) ps[tid] = p[(l0 + tid) * 32 + b];
  __syncthreads();
  const float* xb = x + ((size_t)l0 * 32 + b) * 512 + tid * 4;
  float ax = 0.f, ay = 0.f, az = 0.f, aw = 0.f;
#pragma unroll 4
  for (int i = 0; i < 64; ++i) {
    float4 v = *(const float4*)(xb + (size_t)i * 32 * 512);
    float pv = ps[i];
    ax = fmaf(pv, v.x, ax); ay = fmaf(pv, v.y, ay);
    az = fmaf(pv, v.z, az); aw = fmaf(pv, v.w, aw);
  }
  float4 r; r.x = ax; r.y = ay; r.z = az; r.w = aw;
  *(float4*)(part + (size_t)blk * 512 + tid * 4) = r;
}

// ------- kernel 6: reduce partials -> ctx, concat action_feature -----------
__global__ __launch_bounds__(256) void k_final(const float* __restrict__ part,
                                               const float* __restrict__ af,
                                               float* __restrict__ out) {
  const int b = blockIdx.x, tid = threadIdx.x;
  float ax = 0.f, ay = 0.f;
#pragma unroll
  for (int ch = 0; ch < 32; ++ch) {
    float2 v = *(const float2*)(part + ((size_t)(b * 32 + ch) * 512) + tid * 2);
    ax += v.x; ay += v.y;
  }
  float2 r; r.x = ax; r.y = ay;
  *(float2*)(out + (size_t)b * 1024 + tid * 2) = r;
  float2 a = *(const float2*)(af + (size_t)b * 512 + tid * 2);
  *(float2*)(out + (size_t)b * 1024 + 512 + tid * 2) = a;
}

extern "C" void kernel_launch(void* const* d_in, const int* in_sizes, int n_in,
                              void* d_out, int out_size, void* d_ws, size_t ws_size,
                              hipStream_t stream) {
  const float* x      = (const float*)d_in[0];
  const int*   mask   = (const int*)d_in[1];
  const float* af     = (const float*)d_in[2];
  const float* hidden = (const float*)d_in[3];
  // d_in[4] = state (unused by reference output)
  const float* W1     = (const float*)d_in[5];
  const float* b1     = (const float*)d_in[6];
  const float* W2     = (const float*)d_in[7];
  // d_in[8] = b2 (softmax-invariant, skipped)
  float* out = (float*)d_out;
  char* ws = (char*)d_ws;
  float*          base  = (float*)(ws + OFF_BASE);
  unsigned short* Wt    = (unsigned short*)(ws + OFF_WT);
  float*          logit = (float*)(ws + OFF_LOGIT);
  float*          p     = (float*)(ws + OFF_P);
  float*          part  = (float*)(ws + OFF_PART);

  k_base   <<<32,   256, 0, stream>>>(hidden, W1, b1, base);
  k_prep_wt<<<16,   256, 0, stream>>>(W1, Wt);
  k_logits <<<512,  512, 0, stream>>>(x, Wt, base, W2, logit);
  k_softmax<<<32,   256, 0, stream>>>(logit, mask, p);
  k_ctx    <<<1024, 128, 0, stream>>>(x, p, part);
  k_final  <<<32,   256, 0, stream>>>(part, af, out);
}

// Round 4
// 107.270 us; speedup vs baseline: 1.1492x; 1.1050x over previous
//
#include <hip/hip_runtime.h>
#include <hip/hip_bf16.h>
#include <stdint.h>

// Problem constants (from reference setup_inputs)
#define L_DIM 2048
#define B_DIM 32
#define E_DIM 512
#define HID_DIM 512
#define M_DIM (L_DIM * B_DIM)   // 65536 rows, row m = l*32 + b

typedef float f32x4 __attribute__((ext_vector_type(4)));
typedef short bf16x8 __attribute__((ext_vector_type(8)));

// ws layout (bytes); requires ws_size >= 3211264 (~3.1 MB) — same as R2/R3 (known OK)
#define OFF_BASE  0         // 32*512 f32          = 65536
#define OFF_WT    65536     // 512*512 bf16        = 524288  -> 589824
#define OFF_LOGIT 589824    // 65536 f32           = 262144  -> 851968
#define OFF_P     851968    // 65536 f32           = 262144  -> 1114112
#define OFF_PART  1114112   // 32*32*512 f32       = 2097152 -> 3211264

__device__ __forceinline__ unsigned short f2bf(float f) {
  unsigned int u = __float_as_uint(f);
  u = (u + 0x7FFFu + ((u >> 16) & 1u)) >> 16;   // RNE
  return (unsigned short)u;
}

__device__ __forceinline__ float tanh_fast(float x) {
  float xc = fminf(fmaxf(x, -15.f), 15.f);
  float e = __expf(2.f * xc);
  return (e - 1.f) * __builtin_amdgcn_rcpf(e + 1.f);
}

// ---------------- kernel 1: base[b][h] = hidden[b]@W1_h + b1 ----------------
__global__ __launch_bounds__(256) void k_base(const float* __restrict__ hidden,
                                              const float* __restrict__ W1,
                                              const float* __restrict__ b1,
                                              float* __restrict__ base) {
  const int b = blockIdx.x;
  const int tid = threadIdx.x;
  __shared__ float hs[HID_DIM];
  {
    float2 v = *(const float2*)(hidden + (size_t)b * 512 + tid * 2);
    hs[tid * 2] = v.x; hs[tid * 2 + 1] = v.y;
  }
  __syncthreads();
  const int h = tid * 2;
  float2 b1v = *(const float2*)(b1 + h);
  float ax = b1v.x, ay = b1v.y;
#pragma unroll 8
  for (int e = 0; e < 512; ++e) {
    float2 w = *(const float2*)(W1 + (size_t)e * 512 + h);
    float hv = hs[e];
    ax = fmaf(hv, w.x, ax);
    ay = fmaf(hv, w.y, ay);
  }
  float2 r; r.x = ax; r.y = ay;
  *(float2*)(base + (size_t)b * 512 + h) = r;
}

// ------- kernel 2: pre-permute W1_e into MFMA-fragment order ------
// Wt unit index (16B units, 2048 per kc): u = (n>>7)*512 + ((n>>4)&7)*64 + lg*16 + (n&15)
// content: 8 bf16 of W1_e[k = kc*32 + lg*8 + j][n]
__global__ __launch_bounds__(256) void k_prep_wt(const float* __restrict__ W1,
                                                 unsigned short* __restrict__ Wt) {
  const int kc = blockIdx.x;   // 16 blocks
  const int tid = threadIdx.x;
  __shared__ unsigned short sh[32][516];   // +4 pad to spread strided col reads
#pragma unroll
  for (int i = 0; i < 16; ++i) {
    int f4 = i * 256 + tid;                 // 4096 float4 total
    int r = f4 >> 7;                        // 0..31
    int c = (f4 & 127) * 4;                 // 0..508
    float4 v = *(const float4*)(W1 + (size_t)(512 + kc * 32 + r) * 512 + c);
    sh[r][c + 0] = f2bf(v.x); sh[r][c + 1] = f2bf(v.y);
    sh[r][c + 2] = f2bf(v.z); sh[r][c + 3] = f2bf(v.w);
  }
  __syncthreads();
#pragma unroll
  for (int i = 0; i < 8; ++i) {
    int u = i * 256 + tid;                  // 0..2047
    int n = ((u >> 9) << 7) + (((u >> 6) & 7) << 4) + (u & 15);
    int k0 = ((u >> 4) & 3) << 3;
    alignas(16) unsigned short tmp[8];
#pragma unroll
    for (int j = 0; j < 8; ++j) tmp[j] = sh[k0 + j][n];
    *(uint4*)(Wt + ((size_t)kc * 2048 + u) * 8) = *(const uint4*)tmp;
  }
}

// ------- kernel 3: fused GEMM + tanh + W2 reduce -> logit[m] ---------------
// BM=64 rows/block, full N=512. 8 waves, each owns a 64x64 tile (N-slice).
// W (B operand) loaded DIRECTLY from global (L2-resident, fragment order) to
// registers — no LDS round-trip. LDS holds only x (4 KB/buf, double-buffered).
// ~120 VGPR/wave -> 2 blocks/CU: cross-block overlap fills barrier drains.
__global__ __launch_bounds__(512, 4) void k_logits(
    const float* __restrict__ x, const unsigned short* __restrict__ Wt,
    const float* __restrict__ base, const float* __restrict__ W2,
    float* __restrict__ logit) {
  __shared__ unsigned short xs[2][2048];    // 64 rows x 32 k, bf16, frag order
  const int tid = threadIdx.x;
  const int m0 = blockIdx.x * 64;
  const int w = tid >> 6, lane = tid & 63;  // w = N-slice 0..7
  const int lg = lane >> 4, l15 = lane & 15;

  // x staging map: thread -> (row, 4-float segment)
  const int row = tid >> 3, seg4 = tid & 7;
  const int seg8 = seg4 >> 1, half = seg4 & 1;
  const float* xsrc = x + (size_t)(m0 + row) * 512 + seg4 * 4;
  const int xsu = ((row >> 4) * 64 + seg8 * 16 + (row & 15)) * 8 + half * 4; // ushort idx

  // B fragment base units (per ni), +lane gives the 16B unit
  int ub[4];
#pragma unroll
  for (int ni = 0; ni < 4; ++ni) {
    int nb = w * 64 + ni * 16;
    ub[ni] = ((nb >> 7) << 9) + (((nb >> 4) & 7) << 6);
  }

  // ---- prologue: stage kc=0 x-chunk ----
  {
    float4 v = *(const float4*)xsrc;
    uint2 pk;
    pk.x = (unsigned)f2bf(v.x) | ((unsigned)f2bf(v.y) << 16);
    pk.y = (unsigned)f2bf(v.z) | ((unsigned)f2bf(v.w) << 16);
    *(uint2*)(&xs[0][xsu]) = pk;
  }
  __syncthreads();

  f32x4 acc[4][4];
#pragma unroll
  for (int mi = 0; mi < 4; ++mi)
#pragma unroll
    for (int ni = 0; ni < 4; ++ni) acc[mi][ni] = (f32x4){0.f, 0.f, 0.f, 0.f};

  for (int kc = 0; kc < 16; ++kc) {
    const int cur = kc & 1;
    // B fragments for THIS kc: direct global (L2 hit), perfectly coalesced
    uint4 bw[4];
    const uint4* bsrc = (const uint4*)Wt + (size_t)kc * 2048;
#pragma unroll
    for (int ni = 0; ni < 4; ++ni) bw[ni] = bsrc[ub[ni] + lane];
    // x prefetch for next kc
    float4 nx;
    if (kc < 15) nx = *(const float4*)(xsrc + (kc + 1) * 32);
    // A fragments from LDS (lane-linear, conflict-free)
    bf16x8 af[4];
#pragma unroll
    for (int mi = 0; mi < 4; ++mi)
      af[mi] = *(const bf16x8*)(&xs[cur][(mi * 64 + lane) * 8]);
#pragma unroll
    for (int mi = 0; mi < 4; ++mi)
#pragma unroll
      for (int ni = 0; ni < 4; ++ni)
        acc[mi][ni] = __builtin_amdgcn_mfma_f32_16x16x32_bf16(
            af[mi], *(const bf16x8*)(&bw[ni]), acc[mi][ni], 0, 0, 0);
    if (kc < 15) {
      uint2 pk;
      pk.x = (unsigned)f2bf(nx.x) | ((unsigned)f2bf(nx.y) << 16);
      pk.y = (unsigned)f2bf(nx.z) | ((unsigned)f2bf(nx.w) << 16);
      *(uint2*)(&xs[cur ^ 1][xsu]) = pk;
    }
    __syncthreads();
  }

  // ---- epilogue: pre += base; tanh; dot with W2 slice; reduce ----
  float w2v[4];
#pragma unroll
  for (int ni = 0; ni < 4; ++ni) w2v[ni] = W2[w * 64 + ni * 16 + l15];
  float lsum[4][4];
#pragma unroll
  for (int mi = 0; mi < 4; ++mi) {
#pragma unroll
    for (int rg = 0; rg < 4; ++rg) {
      int m = m0 + mi * 16 + lg * 4 + rg;
      int bb = m & 31;
      const float* brow = base + (size_t)bb * 512 + w * 64;
      float s = 0.f;
#pragma unroll
      for (int ni = 0; ni < 4; ++ni) {
        float pre = acc[mi][ni][rg] + brow[ni * 16 + l15];
        s = fmaf(tanh_fast(pre), w2v[ni], s);
      }
      lsum[mi][rg] = s;
    }
  }
  // reduce the 16-col partial dots within lane groups, then across 8 waves
  float (*lred)[64] = (float (*)[64])xs;   // [w][row64], 2 KB scratch (xs dead)
#pragma unroll
  for (int mi = 0; mi < 4; ++mi)
#pragma unroll
    for (int rg = 0; rg < 4; ++rg) {
      float v = lsum[mi][rg];
      v += __shfl_xor(v, 1); v += __shfl_xor(v, 2);
      v += __shfl_xor(v, 4); v += __shfl_xor(v, 8);
      if (l15 == 0) lred[w][mi * 16 + lg * 4 + rg] = v;
    }
  __syncthreads();
  if (tid < 64) {
    float v = 0.f;
#pragma unroll
    for (int wq = 0; wq < 8; ++wq) v += lred[wq][tid];
    logit[m0 + tid] = v;
  }
}

// ---------------- kernel 4: masked softmax over L per b ----------------
__global__ __launch_bounds__(256) void k_softmax(const float* __restrict__ logit,
                                                 const int* __restrict__ mask,
                                                 float* __restrict__ p) {
  const int b = blockIdx.x, tid = threadIdx.x;
  float lv[8]; float mx = -3.0e38f;
#pragma unroll
  for (int i = 0; i < 8; ++i) {
    int idx = (tid + i * 256) * 32 + b;
    float v = (mask[idx] != 0) ? logit[idx] : -1.0e10f;
    lv[i] = v; mx = fmaxf(mx, v);
  }
  __shared__ float red[8];
  for (int d = 1; d < 64; d <<= 1) mx = fmaxf(mx, __shfl_xor(mx, d));
  if ((tid & 63) == 0) red[tid >> 6] = mx;
  __syncthreads();
  mx = fmaxf(fmaxf(red[0], red[1]), fmaxf(red[2], red[3]));
  float s = 0.f;
#pragma unroll
  for (int i = 0; i < 8; ++i) { lv[i] = __expf(lv[i] - mx); s += lv[i]; }
  for (int d = 1; d < 64; d <<= 1) s += __shfl_xor(s, d);
  __syncthreads();
  if ((tid & 63) == 0) red[4 + (tid >> 6)] = s;
  __syncthreads();
  s = (red[4] + red[5]) + (red[6] + red[7]);
  float inv = 1.f / s;
#pragma unroll
  for (int i = 0; i < 8; ++i) {
    int idx = (tid + i * 256) * 32 + b;
    p[idx] = lv[i] * inv;
  }
}

// ------- kernel 5: partial ctx: part[b][ch][e] = sum_{l in ch} p*x ---------
__global__ __launch_bounds__(128) void k_ctx(const float* __restrict__ x,
                                             const float* __restrict__ p,
                                             float* __restrict__ part) {
  const int blk = blockIdx.x;            // 1024 = 32 b * 32 chunks
  const int b = blk >> 5, ch = blk & 31;
  const int tid = threadIdx.x;           // 128 threads, float4 each
  __shared__ float ps[64];
  const int l0 = ch * 64;
  if (tid < 64) ps[tid] = p[(l0 + tid) * 32 + b];
  __syncthreads();
  const float* xb = x + ((size_t)l0 * 32 + b) * 512 + tid * 4;
  float ax = 0.f, ay = 0.f, az = 0.f, aw = 0.f;
#pragma unroll 4
  for (int i = 0; i < 64; ++i) {
    float4 v = *(const float4*)(xb + (size_t)i * 32 * 512);
    float pv = ps[i];
    ax = fmaf(pv, v.x, ax); ay = fmaf(pv, v.y, ay);
    az = fmaf(pv, v.z, az); aw = fmaf(pv, v.w, aw);
  }
  float4 r; r.x = ax; r.y = ay; r.z = az; r.w = aw;
  *(float4*)(part + (size_t)blk * 512 + tid * 4) = r;
}

// ------- kernel 6: reduce partials -> ctx, concat action_feature -----------
__global__ __launch_bounds__(256) void k_final(const float* __restrict__ part,
                                               const float* __restrict__ af,
                                               float* __restrict__ out) {
  const int b = blockIdx.x, tid = threadIdx.x;
  float ax = 0.f, ay = 0.f;
#pragma unroll
  for (int ch = 0; ch < 32; ++ch) {
    float2 v = *(const float2*)(part + ((size_t)(b * 32 + ch) * 512) + tid * 2);
    ax += v.x; ay += v.y;
  }
  float2 r; r.x = ax; r.y = ay;
  *(float2*)(out + (size_t)b * 1024 + tid * 2) = r;
  float2 a = *(const float2*)(af + (size_t)b * 512 + tid * 2);
  *(float2*)(out + (size_t)b * 1024 + 512 + tid * 2) = a;
}

extern "C" void kernel_launch(void* const* d_in, const int* in_sizes, int n_in,
                              void* d_out, int out_size, void* d_ws, size_t ws_size,
                              hipStream_t stream) {
  const float* x      = (const float*)d_in[0];
  const int*   mask   = (const int*)d_in[1];
  const float* af     = (const float*)d_in[2];
  const float* hidden = (const float*)d_in[3];
  // d_in[4] = state (unused by reference output)
  const float* W1     = (const float*)d_in[5];
  const float* b1     = (const float*)d_in[6];
  const float* W2     = (const float*)d_in[7];
  // d_in[8] = b2 (softmax-invariant, skipped)
  float* out = (float*)d_out;
  char* ws = (char*)d_ws;
  float*          base  = (float*)(ws + OFF_BASE);
  unsigned short* Wt    = (unsigned short*)(ws + OFF_WT);
  float*          logit = (float*)(ws + OFF_LOGIT);
  float*          p     = (float*)(ws + OFF_P);
  float*          part  = (float*)(ws + OFF_PART);

  k_base   <<<32,   256, 0, stream>>>(hidden, W1, b1, base);
  k_prep_wt<<<16,   256, 0, stream>>>(W1, Wt);
  k_logits <<<1024, 512, 0, stream>>>(x, Wt, base, W2, logit);
  k_softmax<<<32,   256, 0, stream>>>(logit, mask, p);
  k_ctx    <<<1024, 128, 0, stream>>>(x, p, part);
  k_final  <<<32,   256, 0, stream>>>(part, af, out);
}